// Round 10
// baseline (136.062 us; speedup 1.0000x reference)
//
#include <hip/hip_runtime.h>
#include <hip/hip_bf16.h>

#define BATCH 256
#define NQ 1000
#define NC 80
#define QC 80000      // NQ*NC
#define KTOP 300
#define NT 1024
#define NBINS 4096
#define CAP 1024
#define T0 2.55f      // static pre-threshold: ~431 exp. candidates/batch, >=300 at -6.3 sigma

// order-preserving map f32 -> u32 (monotone: larger float -> larger uint)
__device__ __forceinline__ unsigned mono_key(float x) {
    unsigned u = __float_as_uint(x);
    return (u & 0x80000000u) ? ~u : (u | 0x80000000u);
}
__device__ __forceinline__ float inv_key(unsigned k) {
    unsigned u = (k & 0x80000000u) ? (k & 0x7FFFFFFFu) : ~k;
    return __uint_as_float(u);
}

// Bit-exact replica of XLA's logistic: 0.5 + 0.5*tanh(0.5*x)  (verified absmax 0.0)
__device__ __forceinline__ float ref_sigmoid(float x) {
    float in = __fmul_rn(0.5f, x);
    float xc = fminf(fmaxf(in, -7.90531110763549805f), 7.90531110763549805f);
    float x2 = __fmul_rn(xc, xc);
    float p = fmaf(x2, -2.76076847742355e-16f, 2.00018790482477e-13f);
    p = fmaf(x2, p, -8.60467152213735e-11f);
    p = fmaf(x2, p,  5.12229709037114e-08f);
    p = fmaf(x2, p,  1.48572235717979e-05f);
    p = fmaf(x2, p,  6.37261928875436e-04f);
    p = fmaf(x2, p,  4.89352455891786e-03f);
    float num = __fmul_rn(xc, p);
    float den = fmaf(x2, 1.19825839466702e-06f, 1.18534705686654e-04f);
    den = fmaf(x2, den, 2.26843463243900e-03f);
    den = fmaf(x2, den, 4.89352518554385e-03f);
    float t = num / den;
    t = (fabsf(in) < 0.0004f) ? in : t;
    return __fadd_rn(0.5f, __fmul_rn(0.5f, t));
}

__device__ __forceinline__ void emit(const float* __restrict__ boxes,
                                     const float* __restrict__ sizes,
                                     float* __restrict__ out,
                                     int b, unsigned rank, unsigned long long cd) {
    unsigned sk = (unsigned)(cd >> 32);
    unsigned idx = ~((unsigned)cd);
    float score = inv_key(sk);
    unsigned label = idx % NC;
    unsigned qi = idx / NC;
    float4 bx = ((const float4*)boxes)[(size_t)b * NQ + qi];
    float W = sizes[b * 2 + 0];
    float H = sizes[b * 2 + 1];
    int o = b * KTOP + (int)rank;
    out[o] = (float)label;
    float* ob = out + BATCH * KTOP;
    ob[(size_t)o * 4 + 0] = (bx.x - 0.5f * bx.z) * W;
    ob[(size_t)o * 4 + 1] = (bx.y - 0.5f * bx.w) * H;
    ob[(size_t)o * 4 + 2] = (bx.x + 0.5f * bx.z) * W;
    ob[(size_t)o * 4 + 3] = (bx.y + 0.5f * bx.w) * H;
    float* os = out + BATCH * KTOP * 5;
    os[o] = score;
}

__global__ __launch_bounds__(NT)
void rtdetr_post_kernel(const float* __restrict__ logits,
                        const float* __restrict__ boxes,
                        const float* __restrict__ sizes,
                        float* __restrict__ out) {
    __shared__ unsigned long long cand[CAP];
    __shared__ unsigned hist[NBINS];     // fallback only
    __shared__ unsigned scan[NT];        // fallback only
    __shared__ unsigned s_tbin, s_count;

    const int b = blockIdx.x;
    const int tid = threadIdx.x;
    const float4* lg4 = (const float4*)(logits + (size_t)b * QC);

    if (tid == 0) s_count = 0;
    __syncthreads();

    // ---- common path: streaming threshold scan, 4 loads in flight/lane ----
    const float4 sent = make_float4(-1e30f, -1e30f, -1e30f, -1e30f);
    for (int i = tid; i < QC / 4; i += 4 * NT) {
        const int i1 = i + NT, i2 = i + 2 * NT, i3 = i + 3 * NT;
        float4 v0 = lg4[i];
        float4 v1 = (i1 < QC / 4) ? lg4[i1] : sent;
        float4 v2 = (i2 < QC / 4) ? lg4[i2] : sent;
        float4 v3 = (i3 < QC / 4) ? lg4[i3] : sent;
        float4 vv[4] = {v0, v1, v2, v3};
        int ii[4] = {i, i1, i2, i3};
        #pragma unroll
        for (int m = 0; m < 4; ++m) {
            float xs[4] = {vv[m].x, vv[m].y, vv[m].z, vv[m].w};
            #pragma unroll
            for (int j = 0; j < 4; ++j) {
                if (xs[j] >= T0) {
                    unsigned pos = atomicAdd(&s_count, 1u);
                    if (pos < CAP) {
                        unsigned sk = mono_key(ref_sigmoid(xs[j]));
                        unsigned idx = (unsigned)(ii[m] * 4 + j);
                        cand[pos] = ((unsigned long long)sk << 32) | (unsigned)(~idx);
                    }
                }
            }
        }
    }
    __syncthreads();
    unsigned cnt = s_count;

    // ---- exact fallback (never taken for this data): histogram threshold ----
    if (cnt < KTOP || cnt > CAP) {
        for (int i = tid; i < NBINS; i += NT) hist[i] = 0;
        if (tid == 0) s_count = 0;
        __syncthreads();
        for (int i = tid; i < QC / 4; i += NT) {
            float4 v = lg4[i];
            atomicAdd(&hist[mono_key(v.x) >> 20], 1u);
            atomicAdd(&hist[mono_key(v.y) >> 20], 1u);
            atomicAdd(&hist[mono_key(v.z) >> 20], 1u);
            atomicAdd(&hist[mono_key(v.w) >> 20], 1u);
        }
        __syncthreads();
        unsigned h0 = hist[tid * 4 + 0], h1 = hist[tid * 4 + 1];
        unsigned h2 = hist[tid * 4 + 2], h3 = hist[tid * 4 + 3];
        scan[tid] = h0 + h1 + h2 + h3;
        __syncthreads();
        for (int off = 1; off < NT; off <<= 1) {
            unsigned v = (tid + off < NT) ? scan[tid + off] : 0u;
            __syncthreads();
            scan[tid] += v;
            __syncthreads();
        }
        unsigned run = (tid + 1 < NT) ? scan[tid + 1] : 0u;
        unsigned hs[4] = {h3, h2, h1, h0};
        #pragma unroll
        for (int j = 0; j < 4; ++j) {
            unsigned bin = (unsigned)(tid * 4 + (3 - j));
            if (run < KTOP && KTOP <= run + hs[j]) s_tbin = bin;
            run += hs[j];
        }
        __syncthreads();
        unsigned thresh = s_tbin << 20;
        thresh = (thresh >= 4096u) ? thresh - 4096u : 0u;
        for (int i = tid; i < QC / 4; i += NT) {
            float4 v = lg4[i];
            float xs[4] = {v.x, v.y, v.z, v.w};
            #pragma unroll
            for (int j = 0; j < 4; ++j) {
                if (mono_key(xs[j]) >= thresh) {
                    unsigned pos = atomicAdd(&s_count, 1u);
                    if (pos < CAP) {
                        unsigned sk = mono_key(ref_sigmoid(xs[j]));
                        unsigned idx = (unsigned)(i * 4 + j);
                        cand[pos] = ((unsigned long long)sk << 32) | (unsigned)(~idx);
                    }
                }
            }
        }
        __syncthreads();
        cnt = s_count; if (cnt > CAP) cnt = CAP;
    }

    // ---- rank selection (rank = #keys greater; unique keys -> unique ranks)
    if (cnt <= 512) {
        // 2-way split: lane pairs share a candidate, halve the j-loop.
        // Uniform trip count (no divergence); 2 LDS addresses/wave = free.
        const int c = tid >> 1;
        const int h = tid & 1;
        unsigned long long my = (c < (int)cnt) ? cand[c] : 0ull;
        const unsigned half_n = (cnt + 1) >> 1;
        const unsigned j0 = h * half_n;
        unsigned r = 0;
        for (unsigned k = 0; k < half_n; ++k) {
            unsigned j = j0 + k;
            unsigned long long v = (j < cnt) ? cand[j] : 0ull;
            r += (v > my) ? 1u : 0u;
        }
        r += __shfl_xor(r, 1);
        if (h == 0 && c < (int)cnt && r < KTOP)
            emit(boxes, sizes, out, b, r, my);
    } else if (tid < (int)cnt) {
        unsigned long long my = cand[tid];
        unsigned rank = 0;
        for (unsigned j = 0; j < cnt; ++j) rank += (cand[j] > my) ? 1u : 0u;
        if (rank < KTOP)
            emit(boxes, sizes, out, b, rank, my);
    }
}

extern "C" void kernel_launch(void* const* d_in, const int* in_sizes, int n_in,
                              void* d_out, int out_size, void* d_ws, size_t ws_size,
                              hipStream_t stream) {
    const float* logits = (const float*)d_in[0];
    const float* boxes  = (const float*)d_in[1];
    const float* sizes  = (const float*)d_in[2];
    float* out = (float*)d_out;
    rtdetr_post_kernel<<<BATCH, NT, 0, stream>>>(logits, boxes, sizes, out);
}

// Round 11
// 126.695 us; speedup vs baseline: 1.0739x; 1.0739x over previous
//
#include <hip/hip_runtime.h>
#include <hip/hip_bf16.h>

#define BATCH 256
#define NQ 1000
#define NC 80
#define QC 80000      // NQ*NC
#define KTOP 300
#define NT 1024
#define NBINS 4096
#define CAP 1024
#define T0 2.55f      // static pre-threshold: ~431 exp. candidates/batch, >=300 at -6.3 sigma

// order-preserving map f32 -> u32 (monotone: larger float -> larger uint)
__device__ __forceinline__ unsigned mono_key(float x) {
    unsigned u = __float_as_uint(x);
    return (u & 0x80000000u) ? ~u : (u | 0x80000000u);
}
__device__ __forceinline__ float inv_key(unsigned k) {
    unsigned u = (k & 0x80000000u) ? (k & 0x7FFFFFFFu) : ~k;
    return __uint_as_float(u);
}

// Bit-exact replica of XLA's logistic: 0.5 + 0.5*tanh(0.5*x)  (verified absmax 0.0)
__device__ __forceinline__ float ref_sigmoid(float x) {
    float in = __fmul_rn(0.5f, x);
    float xc = fminf(fmaxf(in, -7.90531110763549805f), 7.90531110763549805f);
    float x2 = __fmul_rn(xc, xc);
    float p = fmaf(x2, -2.76076847742355e-16f, 2.00018790482477e-13f);
    p = fmaf(x2, p, -8.60467152213735e-11f);
    p = fmaf(x2, p,  5.12229709037114e-08f);
    p = fmaf(x2, p,  1.48572235717979e-05f);
    p = fmaf(x2, p,  6.37261928875436e-04f);
    p = fmaf(x2, p,  4.89352455891786e-03f);
    float num = __fmul_rn(xc, p);
    float den = fmaf(x2, 1.19825839466702e-06f, 1.18534705686654e-04f);
    den = fmaf(x2, den, 2.26843463243900e-03f);
    den = fmaf(x2, den, 4.89352518554385e-03f);
    float t = num / den;
    t = (fabsf(in) < 0.0004f) ? in : t;
    return __fadd_rn(0.5f, __fmul_rn(0.5f, t));
}

__global__ __launch_bounds__(NT)
void rtdetr_post_kernel(const float* __restrict__ logits,
                        const float* __restrict__ boxes,
                        const float* __restrict__ sizes,
                        float* __restrict__ out) {
    __shared__ unsigned long long cand[CAP];
    __shared__ unsigned hist[NBINS];     // fallback only
    __shared__ unsigned scan[NT];        // fallback only
    __shared__ unsigned s_tbin, s_count;

    const int b = blockIdx.x;
    const int tid = threadIdx.x;
    const float4* lg4 = (const float4*)(logits + (size_t)b * QC);

    if (tid == 0) s_count = 0;
    __syncthreads();

    // ---- common path: single streaming read, static threshold.
    // 2x unrolled: both float4 loads issued back-to-back (2 in flight/lane)
    // so 16 waves/CU cover the ~375ns memory latency at ~25 GB/s/CU.
    for (int i = tid; i < QC / 4; i += 2 * NT) {
        float4 a = lg4[i];
        const int i2 = i + NT;
        const bool hb = (i2 < QC / 4);
        float4 bv = hb ? lg4[i2] : make_float4(-1e30f, -1e30f, -1e30f, -1e30f);
        float as[4] = {a.x, a.y, a.z, a.w};
        #pragma unroll
        for (int j = 0; j < 4; ++j) {
            if (as[j] >= T0) {
                unsigned pos = atomicAdd(&s_count, 1u);
                if (pos < CAP) {
                    unsigned sk = mono_key(ref_sigmoid(as[j]));
                    unsigned idx = (unsigned)(i * 4 + j);
                    cand[pos] = ((unsigned long long)sk << 32) | (unsigned)(~idx);
                }
            }
        }
        float bs[4] = {bv.x, bv.y, bv.z, bv.w};
        #pragma unroll
        for (int j = 0; j < 4; ++j) {
            if (bs[j] >= T0) {
                unsigned pos = atomicAdd(&s_count, 1u);
                if (pos < CAP) {
                    unsigned sk = mono_key(ref_sigmoid(bs[j]));
                    unsigned idx = (unsigned)(i2 * 4 + j);
                    cand[pos] = ((unsigned long long)sk << 32) | (unsigned)(~idx);
                }
            }
        }
    }
    __syncthreads();
    unsigned cnt = s_count;

    // ---- exact fallback (never taken for this data): histogram-based threshold ----
    if (cnt < KTOP || cnt > CAP) {
        for (int i = tid; i < NBINS; i += NT) hist[i] = 0;
        if (tid == 0) s_count = 0;
        __syncthreads();
        for (int i = tid; i < QC / 4; i += NT) {
            float4 v = lg4[i];
            atomicAdd(&hist[mono_key(v.x) >> 20], 1u);
            atomicAdd(&hist[mono_key(v.y) >> 20], 1u);
            atomicAdd(&hist[mono_key(v.z) >> 20], 1u);
            atomicAdd(&hist[mono_key(v.w) >> 20], 1u);
        }
        __syncthreads();
        unsigned h0 = hist[tid * 4 + 0], h1 = hist[tid * 4 + 1];
        unsigned h2 = hist[tid * 4 + 2], h3 = hist[tid * 4 + 3];
        scan[tid] = h0 + h1 + h2 + h3;
        __syncthreads();
        for (int off = 1; off < NT; off <<= 1) {
            unsigned v = (tid + off < NT) ? scan[tid + off] : 0u;
            __syncthreads();
            scan[tid] += v;
            __syncthreads();
        }
        unsigned run = (tid + 1 < NT) ? scan[tid + 1] : 0u;
        unsigned hs[4] = {h3, h2, h1, h0};
        #pragma unroll
        for (int j = 0; j < 4; ++j) {
            unsigned bin = (unsigned)(tid * 4 + (3 - j));
            if (run < KTOP && KTOP <= run + hs[j]) s_tbin = bin;
            run += hs[j];
        }
        __syncthreads();
        unsigned thresh = s_tbin << 20;
        thresh = (thresh >= 4096u) ? thresh - 4096u : 0u;
        for (int i = tid; i < QC / 4; i += NT) {
            float4 v = lg4[i];
            float xs[4] = {v.x, v.y, v.z, v.w};
            #pragma unroll
            for (int j = 0; j < 4; ++j) {
                if (mono_key(xs[j]) >= thresh) {
                    unsigned pos = atomicAdd(&s_count, 1u);
                    if (pos < CAP) {
                        unsigned sk = mono_key(ref_sigmoid(xs[j]));
                        unsigned idx = (unsigned)(i * 4 + j);
                        cand[pos] = ((unsigned long long)sk << 32) | (unsigned)(~idx);
                    }
                }
            }
        }
        __syncthreads();
        cnt = s_count; if (cnt > CAP) cnt = CAP;
    }

    // ---- rank selection: rank = #keys greater; unique keys -> unique ranks ----
    if (tid < (int)cnt) {
        unsigned long long my = cand[tid];
        unsigned rank = 0;
        for (unsigned j = 0; j < cnt; ++j) rank += (cand[j] > my) ? 1u : 0u;
        if (rank < KTOP) {
            unsigned sk = (unsigned)(my >> 32);
            unsigned idx = ~((unsigned)my);
            float score = inv_key(sk);
            unsigned label = idx % NC;
            unsigned qi = idx / NC;
            float4 bx = ((const float4*)boxes)[(size_t)b * NQ + qi];
            float W = sizes[b * 2 + 0];
            float H = sizes[b * 2 + 1];
            float x0 = (bx.x - 0.5f * bx.z) * W;
            float y0 = (bx.y - 0.5f * bx.w) * H;
            float x1 = (bx.x + 0.5f * bx.z) * W;
            float y1 = (bx.y + 0.5f * bx.w) * H;
            int o = b * KTOP + (int)rank;
            out[o] = (float)label;
            float* ob = out + BATCH * KTOP;
            ob[(size_t)o * 4 + 0] = x0;
            ob[(size_t)o * 4 + 1] = y0;
            ob[(size_t)o * 4 + 2] = x1;
            ob[(size_t)o * 4 + 3] = y1;
            float* os = out + BATCH * KTOP * 5;
            os[o] = score;
        }
    }
}

extern "C" void kernel_launch(void* const* d_in, const int* in_sizes, int n_in,
                              void* d_out, int out_size, void* d_ws, size_t ws_size,
                              hipStream_t stream) {
    const float* logits = (const float*)d_in[0];
    const float* boxes  = (const float*)d_in[1];
    const float* sizes  = (const float*)d_in[2];
    float* out = (float*)d_out;
    rtdetr_post_kernel<<<BATCH, NT, 0, stream>>>(logits, boxes, sizes, out);
}